// Round 8
// baseline (24.025 us; speedup 1.0000x reference)
//
#include <hip/hip_runtime.h>

#define N_NEUR 9216   // L*L
#define N_FEAT 1024
#define NBLK   2304   // 9 blocks/CU: better ramp/drain for streaming
#define ROWS   4      // 9216 = 2304 * 4, exact
#define LR 0.1f

typedef float vfloat4 __attribute__((ext_vector_type(4)));

// ---------------------------------------------------------------------------
// Kernel 1: block b computes dist^2 for rows [b*4, b*4+4), writes ONE packed
// min-key to partials[b]. key = (float_bits(dist2)<<32)|row — dist2 >= 0 so
// IEEE bits are monotone as uint; min key == argmin, ties -> smallest row
// (matches jnp.argmin over the monotone sqrt).
// ---------------------------------------------------------------------------
__global__ __launch_bounds__(256) void som_dist4(
    const float* __restrict__ x, const float* __restrict__ W,
    unsigned long long* __restrict__ partials)
{
    const int b  = blockIdx.x;
    const int t  = threadIdx.x;
    const int wv = t >> 6, ln = t & 63;

    __shared__ float red[4][ROWS];

    const vfloat4 xa = reinterpret_cast<const vfloat4*>(x)[t];

    #pragma unroll
    for (int k = 0; k < ROWS; ++k) {
        const int row = b * ROWS + k;
        const vfloat4 w = reinterpret_cast<const vfloat4*>(W + (size_t)row * N_FEAT)[t];
        const vfloat4 d = xa - w;
        float s = d.x * d.x + d.y * d.y + d.z * d.z + d.w * d.w;
        #pragma unroll
        for (int o = 32; o > 0; o >>= 1) s += __shfl_down(s, o);
        if (ln == 0) red[wv][k] = s;
    }
    __syncthreads();

    if (t == 0) {
        unsigned long long lmin = ~0ull;
        #pragma unroll
        for (int k = 0; k < ROWS; ++k) {
            const float tot = red[0][k] + red[1][k] + red[2][k] + red[3][k];
            const unsigned long long key =
                ((unsigned long long)__float_as_uint(tot) << 32)
                | (unsigned)(b * ROWS + k);
            lmin = key < lmin ? key : lmin;
        }
        partials[b] = lmin;
    }
}

// ---------------------------------------------------------------------------
// Kernel 2: block b prefetches its 4 W rows into registers (independent of
// bmu), then redundantly min-reduces the 2304 partials (18 KB, L2 broadcast)
// -> bmu, then updates:  W_new = W + LR * exp(-nhb[bmu][row]/2) * (x - W).
// Plain (cached, writeback) stores: out lands dirty in L2/L3 and flushes
// lazily — kernel retires at cache rate, not HBM rate. (A/B vs R7's
// nontemporal stores, which forced every line through HBM.)
// ---------------------------------------------------------------------------
__global__ __launch_bounds__(256) void som_update4(
    const float* __restrict__ x, const float* __restrict__ W,
    const float* __restrict__ nhb,
    const unsigned long long* __restrict__ partials,
    float* __restrict__ out)
{
    const int b  = blockIdx.x;
    const int t  = threadIdx.x;
    const int wv = t >> 6, ln = t & 63;

    __shared__ unsigned long long wmin[4];

    const vfloat4 xa = reinterpret_cast<const vfloat4*>(x)[t];

    // prefetch W rows first — loads don't depend on bmu, hide argmin latency
    vfloat4 wrow[ROWS];
    #pragma unroll
    for (int k = 0; k < ROWS; ++k)
        wrow[k] = reinterpret_cast<const vfloat4*>(W + (size_t)(b * ROWS + k) * N_FEAT)[t];

    // redundant argmin over 2304 packed keys (2304 = 9 * 256)
    unsigned long long m = ~0ull;
    #pragma unroll
    for (int i = 0; i < NBLK / 256; ++i) {
        const unsigned long long k = partials[t + i * 256];
        m = k < m ? k : m;
    }
    #pragma unroll
    for (int o = 32; o > 0; o >>= 1) {
        const unsigned long long k = __shfl_down(m, o);
        m = k < m ? k : m;
    }
    if (ln == 0) wmin[wv] = m;
    __syncthreads();
    m = wmin[0];
    #pragma unroll
    for (int w2 = 1; w2 < 4; ++w2) m = wmin[w2] < m ? wmin[w2] : m;
    const unsigned bmu = (unsigned)(m & 0xFFFFFFFFu);

    #pragma unroll
    for (int k = 0; k < ROWS; ++k) {
        const int row = b * ROWS + k;
        const float lh = LR * expf(-0.5f * nhb[(size_t)bmu * N_NEUR + row]);
        const vfloat4 w = wrow[k];
        const vfloat4 r = w + lh * (xa - w);
        reinterpret_cast<vfloat4*>(out + (size_t)row * N_FEAT)[t] = r;
    }
}

extern "C" void kernel_launch(void* const* d_in, const int* in_sizes, int n_in,
                              void* d_out, int out_size, void* d_ws, size_t ws_size,
                              hipStream_t stream)
{
    const float* x   = (const float*)d_in[0];
    const float* W   = (const float*)d_in[1];
    const float* nhb = (const float*)d_in[2];
    float* out       = (float*)d_out;
    unsigned long long* partials = (unsigned long long*)d_ws;

    som_dist4<<<NBLK, 256, 0, stream>>>(x, W, partials);
    som_update4<<<NBLK, 256, 0, stream>>>(x, W, nhb, partials, out);
}